// Round 10
// baseline (3836.337 us; speedup 1.0000x reference)
//
#include <hip/hip_runtime.h>
#include <hip/hip_bf16.h>

// GNODE fully fused: y' = relu(y@W1+b1)@W2+b2, RK4(3/8) x10 steps (h=0.1),
// out = y@Wl+bl.  N=200000 rows, 128 ch, 64 out ch.
//
// Round 10: dual row-tile per wave (r7 base).  r7's limiter: 1KB weight-frag
// LDS read per MFMA = 8cy vs 4cy CU matrix pipe -> hard ~50% ceiling.  Each
// wave now owns TWO 16-row tiles; every weight frag read feeds 2 MFMAs
// (0.5KB/MFMA) -> LDS and matrix pipes balanced.  Register budget paid by
// packing U/V state as bf16 pairs (consumed only via bf16 rounding or small
// h-scaled corrections; error ~2e-3 vs 0.0156 current absmax):
//   arch ~230 (y 64 + U/V 64 + wA/wB 64 + h 32 + frags/misc), acc 128->AGPR.
// 1 wave/SIMD; 256-thread blocks (4 waves share 65KB LDS weights+biases).
// No AGPR pinning games (r9's bulk-pin spilled 336MB: load landing space).
//
// State recurrences (template<MODE>):
//   M1: U<-k1   M2: V<-k2   M3: U<-U+3(V+k3), V<-U-V+k3   M4: y+=h/8(U+k4)
// Layout identity (mfma_f32_16x16x32_bf16, HW-verified m89):
//   D:      ch = 16*mb + 4*(lane>>4) + r,               batch = lane&15
//   B-frag: ch = 32*kb + 16*(j>>2) + 4*(lane>>4)+(j&3),  batch = lane&15
// => frag[e>>3][e&7] = state[e], e = 4*mb + r.  All lane-local.

typedef __attribute__((ext_vector_type(8))) short bf16x8;
typedef __attribute__((ext_vector_type(4))) float f32x4;

constexpr float HS = 0.1f;

#define MFMA_BF16 __builtin_amdgcn_mfma_f32_16x16x32_bf16
#define SBAR() __builtin_amdgcn_sched_barrier(0x6)   // only VALU/SALU may cross

__device__ __forceinline__ short bfs(float f) {
    return (short)__builtin_bit_cast(unsigned short, __float2bfloat16(f));
}
__device__ __forceinline__ unsigned packbf(float a, float b) {   // -> cvt_pk
    unsigned ua = (unsigned)__builtin_bit_cast(unsigned short, __float2bfloat16(a));
    unsigned ub = (unsigned)__builtin_bit_cast(unsigned short, __float2bfloat16(b));
    return ua | (ub << 16);
}
__device__ __forceinline__ float bplo(unsigned u) { return __builtin_bit_cast(float, u << 16); }
__device__ __forceinline__ float bphi(unsigned u) { return __builtin_bit_cast(float, u & 0xffff0000u); }
__device__ __forceinline__ bf16x8 cw(uint4 u) { return __builtin_bit_cast(bf16x8, u); }

// B-frag for kb from y (fp32) + packed-bf16 U/V, RK4 combo fused per mode.
template<int M>
__device__ __forceinline__ bf16x8 build_frag(const float (&y)[32], const unsigned (&U)[16],
                                             const unsigned (&V)[16], int kb) {
    bf16x8 f;
    #pragma unroll
    for (int j = 0; j < 8; ++j) {
        const int e = kb * 8 + j;
        const float Ue = (e & 1) ? bphi(U[e >> 1]) : bplo(U[e >> 1]);
        const float Ve = (e & 1) ? bphi(V[e >> 1]) : bplo(V[e >> 1]);
        float a;
        if (M == 1)      a = y[e];
        else if (M == 2) a = fmaf(HS * (1.f / 3.f), Ue, y[e]);
        else if (M == 3) a = fmaf(-HS * (1.f / 3.f), Ue, fmaf(HS, Ve, y[e]));
        else             a = fmaf(HS, Ve, y[e]);
        f[j] = bfs(a);
    }
    return f;
}

// Mode-fused writeback for one tile; pair p covers elems 2p,2p+1 (e=4*mb+r).
template<int M>
__device__ __forceinline__ void writeback(const f32x4 (&a2)[8], float (&y)[32],
                                          unsigned (&U)[16], unsigned (&V)[16]) {
    #pragma unroll
    for (int p = 0; p < 16; ++p) {
        const int mb = p >> 1, r0 = (p & 1) * 2;
        const float k0 = a2[mb][r0], k1 = a2[mb][r0 + 1];
        if (M == 1)      U[p] = packbf(k0, k1);
        else if (M == 2) V[p] = packbf(k0, k1);
        else if (M == 3) {
            const float u0 = bplo(U[p]), u1 = bphi(U[p]);
            const float v0 = bplo(V[p]), v1 = bphi(V[p]);
            U[p] = packbf(fmaf(3.f, v0 + k0, u0), fmaf(3.f, v1 + k1, u1));
            V[p] = packbf(u0 - v0 + k0, u1 - v1 + k1);
        } else {
            const float u0 = bplo(U[p]), u1 = bphi(U[p]);
            y[2 * p]     = fmaf(HS * 0.125f, u0 + k0, y[2 * p]);
            y[2 * p + 1] = fmaf(HS * 0.125f, u1 + k1, y[2 * p + 1]);
        }
    }
}

// One f-eval for BOTH tiles; each weight-frag group read feeds 16 MFMAs.
template<int M>
__device__ __forceinline__ void feval2(const uint4* __restrict__ sw1,
                                       const uint4* __restrict__ sw2,
                                       const float* __restrict__ sbf, int lane, int g,
                                       float (&yA)[32], unsigned (&UA)[16], unsigned (&VA)[16],
                                       float (&yB)[32], unsigned (&UB)[16], unsigned (&VB)[16])
{
    uint4 wA[8], wB[8];
    f32x4 accA[8], accB[8];
    #pragma unroll
    for (int mb = 0; mb < 8; ++mb) {
        const f32x4 b = *(const f32x4*)&sbf[mb * 16 + g * 4];
        accA[mb] = b; accB[mb] = b;
    }
    #pragma unroll
    for (int mb = 0; mb < 8; ++mb) wA[mb] = sw1[(mb * 4 + 0) * 64 + lane];

    // ---- matmul1: kb groups 0..3 (wA/wB ping-pong, 16 MFMA per group)
    {
        bf16x8 fA = build_frag<M>(yA, UA, VA, 0), fB = build_frag<M>(yB, UB, VB, 0);
        #pragma unroll
        for (int mb = 0; mb < 8; ++mb) wB[mb] = sw1[(mb * 4 + 1) * 64 + lane];
        #pragma unroll
        for (int mb = 0; mb < 8; ++mb) accA[mb] = MFMA_BF16(cw(wA[mb]), fA, accA[mb], 0, 0, 0);
        #pragma unroll
        for (int mb = 0; mb < 8; ++mb) accB[mb] = MFMA_BF16(cw(wA[mb]), fB, accB[mb], 0, 0, 0);
        SBAR();
    }
    {
        bf16x8 fA = build_frag<M>(yA, UA, VA, 1), fB = build_frag<M>(yB, UB, VB, 1);
        #pragma unroll
        for (int mb = 0; mb < 8; ++mb) wA[mb] = sw1[(mb * 4 + 2) * 64 + lane];
        #pragma unroll
        for (int mb = 0; mb < 8; ++mb) accA[mb] = MFMA_BF16(cw(wB[mb]), fA, accA[mb], 0, 0, 0);
        #pragma unroll
        for (int mb = 0; mb < 8; ++mb) accB[mb] = MFMA_BF16(cw(wB[mb]), fB, accB[mb], 0, 0, 0);
        SBAR();
    }
    {
        bf16x8 fA = build_frag<M>(yA, UA, VA, 2), fB = build_frag<M>(yB, UB, VB, 2);
        #pragma unroll
        for (int mb = 0; mb < 8; ++mb) wB[mb] = sw1[(mb * 4 + 3) * 64 + lane];
        #pragma unroll
        for (int mb = 0; mb < 8; ++mb) accA[mb] = MFMA_BF16(cw(wA[mb]), fA, accA[mb], 0, 0, 0);
        #pragma unroll
        for (int mb = 0; mb < 8; ++mb) accB[mb] = MFMA_BF16(cw(wA[mb]), fB, accB[mb], 0, 0, 0);
        SBAR();
    }
    {
        bf16x8 fA = build_frag<M>(yA, UA, VA, 3), fB = build_frag<M>(yB, UB, VB, 3);
        #pragma unroll
        for (int mb = 0; mb < 8; ++mb) wA[mb] = sw2[(mb * 4 + 0) * 64 + lane];   // W2 grp0
        #pragma unroll
        for (int mb = 0; mb < 8; ++mb) accA[mb] = MFMA_BF16(cw(wB[mb]), fA, accA[mb], 0, 0, 0);
        #pragma unroll
        for (int mb = 0; mb < 8; ++mb) accB[mb] = MFMA_BF16(cw(wB[mb]), fB, accB[mb], 0, 0, 0);
        SBAR();
    }

    // ---- relu -> h frags (both tiles); acc2 = b2
    bf16x8 hA[4], hB[4];
    #pragma unroll
    for (int mb = 0; mb < 8; ++mb)
        #pragma unroll
        for (int r = 0; r < 4; ++r) {
            hA[mb >> 1][(mb & 1) * 4 + r] = bfs(fmaxf(accA[mb][r], 0.f));
            hB[mb >> 1][(mb & 1) * 4 + r] = bfs(fmaxf(accB[mb][r], 0.f));
        }
    f32x4 a2A[8], a2B[8];
    #pragma unroll
    for (int mb = 0; mb < 8; ++mb) {
        const f32x4 b = *(const f32x4*)&sbf[128 + mb * 16 + g * 4];
        a2A[mb] = b; a2B[mb] = b;
    }

    // ---- matmul2: kb groups 0..3
    {
        #pragma unroll
        for (int mb = 0; mb < 8; ++mb) wB[mb] = sw2[(mb * 4 + 1) * 64 + lane];
        #pragma unroll
        for (int mb = 0; mb < 8; ++mb) a2A[mb] = MFMA_BF16(cw(wA[mb]), hA[0], a2A[mb], 0, 0, 0);
        #pragma unroll
        for (int mb = 0; mb < 8; ++mb) a2B[mb] = MFMA_BF16(cw(wA[mb]), hB[0], a2B[mb], 0, 0, 0);
        SBAR();
    }
    {
        #pragma unroll
        for (int mb = 0; mb < 8; ++mb) wA[mb] = sw2[(mb * 4 + 2) * 64 + lane];
        #pragma unroll
        for (int mb = 0; mb < 8; ++mb) a2A[mb] = MFMA_BF16(cw(wB[mb]), hA[1], a2A[mb], 0, 0, 0);
        #pragma unroll
        for (int mb = 0; mb < 8; ++mb) a2B[mb] = MFMA_BF16(cw(wB[mb]), hB[1], a2B[mb], 0, 0, 0);
        SBAR();
    }
    {
        #pragma unroll
        for (int mb = 0; mb < 8; ++mb) wB[mb] = sw2[(mb * 4 + 3) * 64 + lane];
        #pragma unroll
        for (int mb = 0; mb < 8; ++mb) a2A[mb] = MFMA_BF16(cw(wA[mb]), hA[2], a2A[mb], 0, 0, 0);
        #pragma unroll
        for (int mb = 0; mb < 8; ++mb) a2B[mb] = MFMA_BF16(cw(wA[mb]), hB[2], a2B[mb], 0, 0, 0);
        SBAR();
    }
    {
        #pragma unroll
        for (int mb = 0; mb < 8; ++mb) a2A[mb] = MFMA_BF16(cw(wB[mb]), hA[3], a2A[mb], 0, 0, 0);
        #pragma unroll
        for (int mb = 0; mb < 8; ++mb) a2B[mb] = MFMA_BF16(cw(wB[mb]), hB[3], a2B[mb], 0, 0, 0);
        SBAR();
    }

    // ---- writebacks (no trailing fence: next feval's loads may hoist here)
    writeback<M>(a2A, yA, UA, VA);
    writeback<M>(a2B, yB, UB, VB);
}

__global__ __launch_bounds__(256) void gnode_kernel(
    const float* __restrict__ x, const uint4* __restrict__ wfr,
    const float* __restrict__ b1, const float* __restrict__ b2,
    const float* __restrict__ bl, float* __restrict__ out, int n)
{
    __shared__ uint4 s_w[4096];      // 64KB: W1 frags [0..2047], W2 [2048..4095]
    __shared__ float s_bf[256];      // 1KB: b1 [0..127], b2 [128..255]

    const int tid  = threadIdx.x;
    const int lane = tid & 63;
    const int wid  = tid >> 6;       // 0..3
    const int g    = lane >> 4;
    const int c16  = lane & 15;
    const int rowA = blockIdx.x * 128 + wid * 32 + c16;   // tile A row
    const int rowB = rowA + 16;                           // tile B row
    const int rcA  = rowA < n ? rowA : n - 1;
    const int rcB  = rowB < n ? rowB : n - 1;

    // ---- stage weights + biases into LDS (one-time, L2/L3-hot)
    #pragma unroll
    for (int i = 0; i < 16; ++i) s_w[i * 256 + tid] = wfr[i * 256 + tid];
    if (tid < 256) s_bf[tid] = (tid < 128) ? b1[tid] : b2[tid - 128];

    // Y^T state, fp32 master: elem e=4*mb+r <-> (ch = 16*mb+4*g+r, batch=row)
    float yA[32], yB[32];
    {
        const f32x4* x4 = (const f32x4*)x;
        #pragma unroll
        for (int cb = 0; cb < 8; ++cb) {
            f32x4 va = x4[(size_t)rcA * 32 + cb * 4 + g];
            f32x4 vb = x4[(size_t)rcB * 32 + cb * 4 + g];
            #pragma unroll
            for (int r = 0; r < 4; ++r) { yA[cb * 4 + r] = va[r]; yB[cb * 4 + r] = vb[r]; }
        }
    }
    __syncthreads();

    const uint4* sw1 = s_w;
    const uint4* sw2 = s_w + 2048;

    unsigned UA[16], VA[16], UB[16], VB[16];

    #pragma unroll 1
    for (int st = 0; st < 10; ++st) {
        feval2<1>(sw1, sw2, s_bf, lane, g, yA, UA, VA, yB, UB, VB);   // U <- k1
        feval2<2>(sw1, sw2, s_bf, lane, g, yA, UA, VA, yB, UB, VB);   // V <- k2
        feval2<3>(sw1, sw2, s_bf, lane, g, yA, UA, VA, yB, UB, VB);   // fold k3
        feval2<4>(sw1, sw2, s_bf, lane, g, yA, UA, VA, yB, UB, VB);   // y += h/8(U+k4)
    }

    // ---- epilogue: out^T = Wl^T y^T + bl  (Wl frags shared by both tiles)
    bf16x8 yfA[4], yfB[4];
    #pragma unroll
    for (int e = 0; e < 32; ++e) {
        yfA[e >> 3][e & 7] = bfs(yA[e]);
        yfB[e >> 3][e & 7] = bfs(yB[e]);
    }
    f32x4 aoA[4], aoB[4];
    {
        const f32x4* bl4 = (const f32x4*)bl;
        #pragma unroll
        for (int mb = 0; mb < 4; ++mb) { aoA[mb] = bl4[mb * 4 + g]; aoB[mb] = aoA[mb]; }
    }
    #pragma unroll
    for (int f = 0; f < 16; ++f) {
        bf16x8 w = cw(wfr[(64 + f) * 64 + lane]);
        aoA[f >> 2] = MFMA_BF16(w, yfA[f & 3], aoA[f >> 2], 0, 0, 0);
        aoB[f >> 2] = MFMA_BF16(w, yfB[f & 3], aoB[f >> 2], 0, 0, 0);
    }
    f32x4* out4 = (f32x4*)out;
    if (rowA < n) {
        #pragma unroll
        for (int mb = 0; mb < 4; ++mb)
            out4[(size_t)rowA * 16 + mb * 4 + g] = aoA[mb];
    }
    if (rowB < n) {
        #pragma unroll
        for (int mb = 0; mb < 4; ++mb)
            out4[(size_t)rowB * 16 + mb * 4 + g] = aoB[mb];
    }
}

// ---- prep: A-frag-linear bf16 weights into d_ws ----
// A-frag (16x32): lane l, elem j:  row = l&15 (+16*mb),
//                                  k   = 32*kb + 16*(j>>2) + 4*(l>>4) + (j&3)
// wfr[f*64+lane] : f 0..31 = W1 (mb=f>>2,kb=f&3), 32..63 = W2, 64..79 = Wl.
__global__ void prep_kernel(const float* __restrict__ W1, const float* __restrict__ W2,
                            const float* __restrict__ Wl, uint4* __restrict__ wfr)
{
    int t = blockIdx.x * 256 + threadIdx.x;
    if (t >= 80 * 64) return;
    int f = t >> 6, lane = t & 63;
    int gq = lane >> 4, c = lane & 15;
    const float* W; int mb, kv, cols;
    if (f < 32)      { W = W1; mb = f >> 2;        kv = f & 3;        cols = 128; }
    else if (f < 64) { W = W2; mb = (f - 32) >> 2; kv = (f - 32) & 3; cols = 128; }
    else             { W = Wl; mb = (f - 64) >> 2; kv = (f - 64) & 3; cols = 64;  }
    int col = mb * 16 + c;               // output-channel (A row)
    unsigned short v[8];
    #pragma unroll
    for (int j = 0; j < 8; ++j) {
        int k = kv * 32 + (j >> 2) * 16 + gq * 4 + (j & 3);
        v[j] = __builtin_bit_cast(unsigned short, __float2bfloat16(W[k * cols + col]));
    }
    uint4 o;
    o.x = (unsigned)v[0] | ((unsigned)v[1] << 16);
    o.y = (unsigned)v[2] | ((unsigned)v[3] << 16);
    o.z = (unsigned)v[4] | ((unsigned)v[5] << 16);
    o.w = (unsigned)v[6] | ((unsigned)v[7] << 16);
    wfr[t] = o;
}

extern "C" void kernel_launch(void* const* d_in, const int* in_sizes, int n_in,
                              void* d_out, int out_size, void* d_ws, size_t ws_size,
                              hipStream_t stream)
{
    const float* x  = (const float*)d_in[0];
    const float* W1 = (const float*)d_in[1];
    const float* b1 = (const float*)d_in[2];
    const float* W2 = (const float*)d_in[3];
    const float* b2 = (const float*)d_in[4];
    const float* Wl = (const float*)d_in[5];
    const float* bl = (const float*)d_in[6];

    const int n = in_sizes[0] / 128;

    uint4* wfr = (uint4*)d_ws;                       // 80*64*16 = 81920 B

    prep_kernel<<<20, 256, 0, stream>>>(W1, W2, Wl, wfr);

    const int nb = (n + 127) / 128;          // 128 rows per block (4 waves x 32)
    gnode_kernel<<<nb, 256, 0, stream>>>(x, wfr, b1, b2, bl, (float*)d_out, n);
}

// Round 12
// 560.285 us; speedup vs baseline: 6.8471x; 6.8471x over previous
//
#include <hip/hip_runtime.h>
#include <hip/hip_bf16.h>

// GNODE fully fused: y' = relu(y@W1+b1)@W2+b2, RK4(3/8) x10 steps (h=0.1),
// out = y@Wl+bl.  N=200000 rows, 128 ch, 64 out ch.
//
// Round 12: SPLIT-CHANNEL WAVE PAIR.  (r7 = LDS-BW-bound at 33% MfmaUtil;
// r9/r11 forced-AGPR pinning spilled / corrupted; r10 dual-tile spilled.)
// Block = 128 threads = 2 waves sharing 16 batch rows.  Wave wid owns
// out-ch [64*wid, 64*wid+64) of BOTH layers:
//   - weights W1-half + W2-half = 32 A-frags = 128 ordinary VGPRs (no LDS
//     weight reads, no pinning).
//   - per-feval cross-channel coupling via bf16 B-frag exchange in LDS:
//     write own 2 frags, __syncthreads, read all 4 (argx for matmul1 input,
//     hx for hidden).  ~4KB LDS traffic/feval (16x less than r7).
//   - state y/U/V covers only own 16 local elems -> 48 regs.
// Barrier safety without parity buffers: each feval has 2 barriers
// (arg-exchange, h-exchange) on ALTERNATING buffers, so a buffer's next
// write is always >=1 barrier after every read of its previous contents.
// Live set ~240 regs -> target 2 waves/SIMD.
//
// State recurrences (template<MODE>):
//   M1: U<-k1   M2: V<-k2   M3: U<-U+3(V+k3), V<-U-V+k3   M4: y+=h/8(U+k4)
// Layout identity (mfma_f32_16x16x32_bf16, HW-verified m89):
//   D:      ch = 16*mb + 4*(lane>>4) + r,               batch = lane&15
//   B-frag: ch = 32*kb + 16*(j>>2) + 4*(lane>>4)+(j&3),  batch = lane&15
// => frag[kb][j] = state[kb*8+j]; wave wid owns global e in [16*wid, 16*wid+16)
//    (local e' = e - 16*wid), i.e. global kb in {2*wid, 2*wid+1}.

typedef __attribute__((ext_vector_type(8))) short bf16x8;
typedef __attribute__((ext_vector_type(4))) float f32x4;

constexpr float HS = 0.1f;

__device__ __forceinline__ short bf16s(float f) {
    unsigned u = __builtin_bit_cast(unsigned, f);
    u += 0x7fffu + ((u >> 16) & 1u);          // RNE (finite data, no NaN)
    return (short)(u >> 16);
}

#define MFMA_BF16 __builtin_amdgcn_mfma_f32_16x16x32_bf16

// B-frag for local kk (0/1) from this wave's 16 local state elems.
template<int M>
__device__ __forceinline__ bf16x8 build_frag(const float (&y)[16], const float (&U)[16],
                                             const float (&V)[16], int kk) {
    bf16x8 f;
    #pragma unroll
    for (int j = 0; j < 8; ++j) {
        const int e = kk * 8 + j;
        float a;
        if (M == 1)      a = y[e];
        else if (M == 2) a = fmaf(HS * (1.f / 3.f), U[e], y[e]);
        else if (M == 3) a = fmaf(-HS * (1.f / 3.f), U[e], fmaf(HS, V[e], y[e]));
        else             a = fmaf(HS, V[e], y[e]);
        f[j] = bf16s(a);
    }
    return f;
}

// One f-eval for this wave's 64-out-ch half.  Weights in registers.
template<int M>
__device__ __forceinline__ void feval(const bf16x8 (&w1r)[16], const bf16x8 (&w2r)[16],
                                      const float* __restrict__ sbf,
                                      uint4 (&argx)[4][64], uint4 (&hx)[4][64],
                                      int lane, int g, int wid,
                                      float (&y)[16], float (&U)[16], float (&V)[16])
{
    // ---- arg exchange: write own 2 frags, barrier, read all 4
    argx[2 * wid + 0][lane] = __builtin_bit_cast(uint4, build_frag<M>(y, U, V, 0));
    argx[2 * wid + 1][lane] = __builtin_bit_cast(uint4, build_frag<M>(y, U, V, 1));
    __syncthreads();
    const bf16x8 fr0 = __builtin_bit_cast(bf16x8, argx[0][lane]);
    const bf16x8 fr1 = __builtin_bit_cast(bf16x8, argx[1][lane]);
    const bf16x8 fr2 = __builtin_bit_cast(bf16x8, argx[2][lane]);
    const bf16x8 fr3 = __builtin_bit_cast(bf16x8, argx[3][lane]);

    // ---- matmul1: acc[mb'] = b1-half + W1-half @ arg   (16 MFMA)
    f32x4 acc[4];
    #pragma unroll
    for (int mb = 0; mb < 4; ++mb)
        acc[mb] = *(const f32x4*)&sbf[wid * 64 + mb * 16 + g * 4];
    #pragma unroll
    for (int mb = 0; mb < 4; ++mb) acc[mb] = MFMA_BF16(w1r[mb * 4 + 0], fr0, acc[mb], 0, 0, 0);
    #pragma unroll
    for (int mb = 0; mb < 4; ++mb) acc[mb] = MFMA_BF16(w1r[mb * 4 + 1], fr1, acc[mb], 0, 0, 0);
    #pragma unroll
    for (int mb = 0; mb < 4; ++mb) acc[mb] = MFMA_BF16(w1r[mb * 4 + 2], fr2, acc[mb], 0, 0, 0);
    #pragma unroll
    for (int mb = 0; mb < 4; ++mb) acc[mb] = MFMA_BF16(w1r[mb * 4 + 3], fr3, acc[mb], 0, 0, 0);

    // ---- relu -> own h frags (local kk: mb' = 2*kk + (j>>2), r = j&3)
    bf16x8 hb0, hb1;
    #pragma unroll
    for (int j = 0; j < 8; ++j) {
        hb0[j] = bf16s(fmaxf(acc[(j >> 2)][j & 3], 0.f));
        hb1[j] = bf16s(fmaxf(acc[2 + (j >> 2)][j & 3], 0.f));
    }

    // ---- h exchange
    hx[2 * wid + 0][lane] = __builtin_bit_cast(uint4, hb0);
    hx[2 * wid + 1][lane] = __builtin_bit_cast(uint4, hb1);
    __syncthreads();
    const bf16x8 h0 = __builtin_bit_cast(bf16x8, hx[0][lane]);
    const bf16x8 h1 = __builtin_bit_cast(bf16x8, hx[1][lane]);
    const bf16x8 h2 = __builtin_bit_cast(bf16x8, hx[2][lane]);
    const bf16x8 h3 = __builtin_bit_cast(bf16x8, hx[3][lane]);

    // ---- matmul2: acc2[mb'] = b2-half + W2-half @ h   (16 MFMA)
    f32x4 acc2[4];
    #pragma unroll
    for (int mb = 0; mb < 4; ++mb)
        acc2[mb] = *(const f32x4*)&sbf[128 + wid * 64 + mb * 16 + g * 4];
    #pragma unroll
    for (int mb = 0; mb < 4; ++mb) acc2[mb] = MFMA_BF16(w2r[mb * 4 + 0], h0, acc2[mb], 0, 0, 0);
    #pragma unroll
    for (int mb = 0; mb < 4; ++mb) acc2[mb] = MFMA_BF16(w2r[mb * 4 + 1], h1, acc2[mb], 0, 0, 0);
    #pragma unroll
    for (int mb = 0; mb < 4; ++mb) acc2[mb] = MFMA_BF16(w2r[mb * 4 + 2], h2, acc2[mb], 0, 0, 0);
    #pragma unroll
    for (int mb = 0; mb < 4; ++mb) acc2[mb] = MFMA_BF16(w2r[mb * 4 + 3], h3, acc2[mb], 0, 0, 0);

    // ---- mode-fused writeback (local e' = 4*mb' + r)
    #pragma unroll
    for (int mb = 0; mb < 4; ++mb)
        #pragma unroll
        for (int r = 0; r < 4; ++r) {
            const int e = mb * 4 + r;
            const float k = acc2[mb][r];
            if (M == 1)      U[e] = k;
            else if (M == 2) V[e] = k;
            else if (M == 3) {
                const float u = U[e], v = V[e];
                U[e] = fmaf(3.f, v + k, u);
                V[e] = u - v + k;
            } else {
                y[e] = fmaf(HS * 0.125f, U[e] + k, y[e]);
            }
        }
}

__global__ __launch_bounds__(128) void gnode_kernel(
    const float* __restrict__ x, const uint4* __restrict__ wfr,
    const float* __restrict__ b1, const float* __restrict__ b2,
    const float* __restrict__ bl, float* __restrict__ out, int n)
{
    __shared__ uint4 argx[4][64];    // 4KB: arg B-frag exchange
    __shared__ uint4 hx[4][64];      // 4KB: hidden B-frag exchange
    __shared__ float s_bf[256];      // 1KB: b1 [0..127], b2 [128..255]

    const int tid  = threadIdx.x;
    const int lane = tid & 63;
    const int wid  = tid >> 6;       // 0/1: which 64-out-ch half this wave owns
    const int g    = lane >> 4;
    const int c16  = lane & 15;
    const int row  = blockIdx.x * 16 + c16;   // this lane's batch row
    const int rowc = row < n ? row : n - 1;

    s_bf[tid]       = b1[tid];
    s_bf[128 + tid] = b2[tid];

    // ---- weights: this wave's halves -> 128 ordinary VGPRs (32 x b128 loads)
    bf16x8 w1r[16], w2r[16];
    #pragma unroll
    for (int f = 0; f < 16; ++f) {
        const int mb = f >> 2, kv = f & 3;                 // global mb = wid*4+mb
        w1r[f] = __builtin_bit_cast(bf16x8, wfr[((wid * 4 + mb) * 4 + kv) * 64 + lane]);
        w2r[f] = __builtin_bit_cast(bf16x8, wfr[(32 + (wid * 4 + mb) * 4 + kv) * 64 + lane]);
    }

    // ---- state: this wave's 16 local elems (ch = 64*wid + 16*(e>>2)+4g+(e&3))
    //      local e' <-> global f32x4 index: rowc*32 + (wid*4 + (e'>>2))*4 + g
    float y[16];
    {
        const f32x4* x4 = (const f32x4*)x;
        #pragma unroll
        for (int cb = 0; cb < 4; ++cb) {
            f32x4 v = x4[(size_t)rowc * 32 + (wid * 4 + cb) * 4 + g];
            y[cb * 4 + 0] = v[0]; y[cb * 4 + 1] = v[1];
            y[cb * 4 + 2] = v[2]; y[cb * 4 + 3] = v[3];
        }
    }
    __syncthreads();

    float U[16], V[16];

    #pragma unroll 1
    for (int st = 0; st < 10; ++st) {
        feval<1>(w1r, w2r, s_bf, argx, hx, lane, g, wid, y, U, V);   // U <- k1
        feval<2>(w1r, w2r, s_bf, argx, hx, lane, g, wid, y, U, V);   // V <- k2
        feval<3>(w1r, w2r, s_bf, argx, hx, lane, g, wid, y, U, V);   // fold k3
        feval<4>(w1r, w2r, s_bf, argx, hx, lane, g, wid, y, U, V);   // y += h/8(U+k4)
    }

    // ---- epilogue: out^T = Wl^T y^T + bl (wave computes out-ch [32*wid,+32))
    argx[2 * wid + 0][lane] = __builtin_bit_cast(uint4, build_frag<1>(y, U, V, 0));
    argx[2 * wid + 1][lane] = __builtin_bit_cast(uint4, build_frag<1>(y, U, V, 1));
    __syncthreads();
    const bf16x8 yf0 = __builtin_bit_cast(bf16x8, argx[0][lane]);
    const bf16x8 yf1 = __builtin_bit_cast(bf16x8, argx[1][lane]);
    const bf16x8 yf2 = __builtin_bit_cast(bf16x8, argx[2][lane]);
    const bf16x8 yf3 = __builtin_bit_cast(bf16x8, argx[3][lane]);

    f32x4 ao[2];
    {
        const f32x4* bl4 = (const f32x4*)bl;
        #pragma unroll
        for (int mb = 0; mb < 2; ++mb) ao[mb] = bl4[(wid * 2 + mb) * 4 + g];
    }
    #pragma unroll
    for (int mb = 0; mb < 2; ++mb) {
        const int fb = 64 + (wid * 2 + mb) * 4;            // Wl frag base
        ao[mb] = MFMA_BF16(__builtin_bit_cast(bf16x8, wfr[(fb + 0) * 64 + lane]), yf0, ao[mb], 0, 0, 0);
        ao[mb] = MFMA_BF16(__builtin_bit_cast(bf16x8, wfr[(fb + 1) * 64 + lane]), yf1, ao[mb], 0, 0, 0);
        ao[mb] = MFMA_BF16(__builtin_bit_cast(bf16x8, wfr[(fb + 2) * 64 + lane]), yf2, ao[mb], 0, 0, 0);
        ao[mb] = MFMA_BF16(__builtin_bit_cast(bf16x8, wfr[(fb + 3) * 64 + lane]), yf3, ao[mb], 0, 0, 0);
    }
    if (row < n) {
        f32x4* out4 = (f32x4*)out;
        #pragma unroll
        for (int mb = 0; mb < 2; ++mb)
            out4[(size_t)row * 16 + (wid * 2 + mb) * 4 + g] = ao[mb];
    }
}

// ---- prep: A-frag-linear bf16 weights into d_ws ----
// A-frag (16x32): lane l, elem j:  row = l&15 (+16*mb),
//                                  k   = 32*kb + 16*(j>>2) + 4*(l>>4) + (j&3)
// wfr[f*64+lane] : f 0..31 = W1 (mb=f>>2,kb=f&3), 32..63 = W2, 64..79 = Wl.
__global__ void prep_kernel(const float* __restrict__ W1, const float* __restrict__ W2,
                            const float* __restrict__ Wl, uint4* __restrict__ wfr)
{
    int t = blockIdx.x * 256 + threadIdx.x;
    if (t >= 80 * 64) return;
    int f = t >> 6, lane = t & 63;
    int gq = lane >> 4, c = lane & 15;
    const float* W; int mb, kv, cols;
    if (f < 32)      { W = W1; mb = f >> 2;        kv = f & 3;        cols = 128; }
    else if (f < 64) { W = W2; mb = (f - 32) >> 2; kv = (f - 32) & 3; cols = 128; }
    else             { W = Wl; mb = (f - 64) >> 2; kv = (f - 64) & 3; cols = 64;  }
    int col = mb * 16 + c;               // output-channel (A row)
    unsigned short v[8];
    #pragma unroll
    for (int j = 0; j < 8; ++j) {
        int k = kv * 32 + (j >> 2) * 16 + gq * 4 + (j & 3);
        unsigned u = __builtin_bit_cast(unsigned, W[k * cols + col]);
        u += 0x7fffu + ((u >> 16) & 1u);
        v[j] = (unsigned short)(u >> 16);
    }
    uint4 o;
    o.x = (unsigned)v[0] | ((unsigned)v[1] << 16);
    o.y = (unsigned)v[2] | ((unsigned)v[3] << 16);
    o.z = (unsigned)v[4] | ((unsigned)v[5] << 16);
    o.w = (unsigned)v[6] | ((unsigned)v[7] << 16);
    wfr[t] = o;
}

extern "C" void kernel_launch(void* const* d_in, const int* in_sizes, int n_in,
                              void* d_out, int out_size, void* d_ws, size_t ws_size,
                              hipStream_t stream)
{
    const float* x  = (const float*)d_in[0];
    const float* W1 = (const float*)d_in[1];
    const float* b1 = (const float*)d_in[2];
    const float* W2 = (const float*)d_in[3];
    const float* b2 = (const float*)d_in[4];
    const float* Wl = (const float*)d_in[5];
    const float* bl = (const float*)d_in[6];

    const int n = in_sizes[0] / 128;

    uint4* wfr = (uint4*)d_ws;                       // 80*64*16 = 81920 B

    prep_kernel<<<20, 256, 0, stream>>>(W1, W2, Wl, wfr);

    const int nb = (n + 15) / 16;            // 16 rows per block (2 waves)
    gnode_kernel<<<nb, 128, 0, stream>>>(x, wfr, b1, b2, bl, (float*)d_out, n);
}

// Round 13
// 489.300 us; speedup vs baseline: 7.8405x; 1.1451x over previous
//
#include <hip/hip_runtime.h>
#include <hip/hip_bf16.h>

// GNODE fully fused: y' = relu(y@W1+b1)@W2+b2, RK4(3/8) x10 steps (h=0.1),
// out = y@Wl+bl.  N=200000 rows, 128 ch, 64 out ch.
//
// Round 13 = r12 (split-channel wave pair; weights land in AGPRs naturally:
// VGPR_Count 116 arch + 128 AGPR, 2 waves/SIMD, zero spill) with the VALU
// hog fixed: r12 measured VALUBusy 54% > MfmaUtil 35%, dominated by the
// 4-5-op bit-twiddle RNE bf16 conversion (~150 ops/feval).  All f32->bf16
// conversions now go through native (__bf16) casts so the compiler emits
// packed v_cvt_pk_bf16_f32 (1 op / 2 elems; conversion loops are laid out
// in adjacent pairs).  Numerically identical (RNE, finite data).
//
// Structure (r12): block = 128 threads = 2 waves sharing 16 batch rows.
// Wave wid owns out-ch [64*wid, 64*wid+64) of BOTH layers:
//   - W1-half + W2-half = 32 A-frags = 128 regs (AGPR-resident, no pinning).
//   - cross-channel coupling via bf16 B-frag exchange in LDS (2 barriers
//     per feval on alternating buffers argx/hx -> WAR-safe).
//   - state y/U/V = own 16 local elems -> 48 regs.
//
// State recurrences (template<MODE>):
//   M1: U<-k1   M2: V<-k2   M3: U<-U+3(V+k3), V<-U-V+k3   M4: y+=h/8(U+k4)
// Layout identity (mfma_f32_16x16x32_bf16, HW-verified m89):
//   D:      ch = 16*mb + 4*(lane>>4) + r,               batch = lane&15
//   B-frag: ch = 32*kb + 16*(j>>2) + 4*(lane>>4)+(j&3),  batch = lane&15
// => frag[kb][j] = state[kb*8+j]; wave wid owns global e in [16*wid,16*wid+16).

typedef __attribute__((ext_vector_type(8))) short bf16x8;
typedef __attribute__((ext_vector_type(4))) float f32x4;

constexpr float HS = 0.1f;

__device__ __forceinline__ short bf16s(float f) {
    return __builtin_bit_cast(short, (__bf16)f);      // fptrunc -> v_cvt_pk_bf16_f32 (paired)
}

#define MFMA_BF16 __builtin_amdgcn_mfma_f32_16x16x32_bf16

// B-frag for local kk (0/1) from this wave's 16 local state elems.
template<int M>
__device__ __forceinline__ bf16x8 build_frag(const float (&y)[16], const float (&U)[16],
                                             const float (&V)[16], int kk) {
    bf16x8 f;
    #pragma unroll
    for (int j = 0; j < 8; ++j) {
        const int e = kk * 8 + j;
        float a;
        if (M == 1)      a = y[e];
        else if (M == 2) a = fmaf(HS * (1.f / 3.f), U[e], y[e]);
        else if (M == 3) a = fmaf(-HS * (1.f / 3.f), U[e], fmaf(HS, V[e], y[e]));
        else             a = fmaf(HS, V[e], y[e]);
        f[j] = bf16s(a);
    }
    return f;
}

// One f-eval for this wave's 64-out-ch half.  Weights in registers (AGPR).
template<int M>
__device__ __forceinline__ void feval(const bf16x8 (&w1r)[16], const bf16x8 (&w2r)[16],
                                      const float* __restrict__ sbf,
                                      uint4 (&argx)[4][64], uint4 (&hx)[4][64],
                                      int lane, int g, int wid,
                                      float (&y)[16], float (&U)[16], float (&V)[16])
{
    // ---- arg exchange: write own 2 frags, barrier, read all 4
    argx[2 * wid + 0][lane] = __builtin_bit_cast(uint4, build_frag<M>(y, U, V, 0));
    argx[2 * wid + 1][lane] = __builtin_bit_cast(uint4, build_frag<M>(y, U, V, 1));
    __syncthreads();
    const bf16x8 fr0 = __builtin_bit_cast(bf16x8, argx[0][lane]);
    const bf16x8 fr1 = __builtin_bit_cast(bf16x8, argx[1][lane]);
    const bf16x8 fr2 = __builtin_bit_cast(bf16x8, argx[2][lane]);
    const bf16x8 fr3 = __builtin_bit_cast(bf16x8, argx[3][lane]);

    // ---- matmul1: acc[mb'] = b1-half + W1-half @ arg   (16 MFMA)
    f32x4 acc[4];
    #pragma unroll
    for (int mb = 0; mb < 4; ++mb)
        acc[mb] = *(const f32x4*)&sbf[wid * 64 + mb * 16 + g * 4];
    #pragma unroll
    for (int mb = 0; mb < 4; ++mb) acc[mb] = MFMA_BF16(w1r[mb * 4 + 0], fr0, acc[mb], 0, 0, 0);
    #pragma unroll
    for (int mb = 0; mb < 4; ++mb) acc[mb] = MFMA_BF16(w1r[mb * 4 + 1], fr1, acc[mb], 0, 0, 0);
    #pragma unroll
    for (int mb = 0; mb < 4; ++mb) acc[mb] = MFMA_BF16(w1r[mb * 4 + 2], fr2, acc[mb], 0, 0, 0);
    #pragma unroll
    for (int mb = 0; mb < 4; ++mb) acc[mb] = MFMA_BF16(w1r[mb * 4 + 3], fr3, acc[mb], 0, 0, 0);

    // ---- relu -> own h frags (adjacent pairs within one acc vector: packable)
    bf16x8 hb0, hb1;
    #pragma unroll
    for (int j = 0; j < 8; ++j) {
        hb0[j] = bf16s(fmaxf(acc[(j >> 2)][j & 3], 0.f));
        hb1[j] = bf16s(fmaxf(acc[2 + (j >> 2)][j & 3], 0.f));
    }

    // ---- h exchange
    hx[2 * wid + 0][lane] = __builtin_bit_cast(uint4, hb0);
    hx[2 * wid + 1][lane] = __builtin_bit_cast(uint4, hb1);
    __syncthreads();
    const bf16x8 h0 = __builtin_bit_cast(bf16x8, hx[0][lane]);
    const bf16x8 h1 = __builtin_bit_cast(bf16x8, hx[1][lane]);
    const bf16x8 h2 = __builtin_bit_cast(bf16x8, hx[2][lane]);
    const bf16x8 h3 = __builtin_bit_cast(bf16x8, hx[3][lane]);

    // ---- matmul2: acc2[mb'] = b2-half + W2-half @ h   (16 MFMA)
    f32x4 acc2[4];
    #pragma unroll
    for (int mb = 0; mb < 4; ++mb)
        acc2[mb] = *(const f32x4*)&sbf[128 + wid * 64 + mb * 16 + g * 4];
    #pragma unroll
    for (int mb = 0; mb < 4; ++mb) acc2[mb] = MFMA_BF16(w2r[mb * 4 + 0], h0, acc2[mb], 0, 0, 0);
    #pragma unroll
    for (int mb = 0; mb < 4; ++mb) acc2[mb] = MFMA_BF16(w2r[mb * 4 + 1], h1, acc2[mb], 0, 0, 0);
    #pragma unroll
    for (int mb = 0; mb < 4; ++mb) acc2[mb] = MFMA_BF16(w2r[mb * 4 + 2], h2, acc2[mb], 0, 0, 0);
    #pragma unroll
    for (int mb = 0; mb < 4; ++mb) acc2[mb] = MFMA_BF16(w2r[mb * 4 + 3], h3, acc2[mb], 0, 0, 0);

    // ---- mode-fused writeback (local e' = 4*mb' + r)
    #pragma unroll
    for (int mb = 0; mb < 4; ++mb)
        #pragma unroll
        for (int r = 0; r < 4; ++r) {
            const int e = mb * 4 + r;
            const float k = acc2[mb][r];
            if (M == 1)      U[e] = k;
            else if (M == 2) V[e] = k;
            else if (M == 3) {
                const float u = U[e], v = V[e];
                U[e] = fmaf(3.f, v + k, u);
                V[e] = u - v + k;
            } else {
                y[e] = fmaf(HS * 0.125f, U[e] + k, y[e]);
            }
        }
}

__global__ __launch_bounds__(128) void gnode_kernel(
    const float* __restrict__ x, const uint4* __restrict__ wfr,
    const float* __restrict__ b1, const float* __restrict__ b2,
    const float* __restrict__ bl, float* __restrict__ out, int n)
{
    __shared__ uint4 argx[4][64];    // 4KB: arg B-frag exchange
    __shared__ uint4 hx[4][64];      // 4KB: hidden B-frag exchange
    __shared__ float s_bf[256];      // 1KB: b1 [0..127], b2 [128..255]

    const int tid  = threadIdx.x;
    const int lane = tid & 63;
    const int wid  = tid >> 6;       // 0/1: which 64-out-ch half this wave owns
    const int g    = lane >> 4;
    const int c16  = lane & 15;
    const int row  = blockIdx.x * 16 + c16;   // this lane's batch row
    const int rowc = row < n ? row : n - 1;

    s_bf[tid]       = b1[tid];
    s_bf[128 + tid] = b2[tid];

    // ---- weights: this wave's halves -> 128 regs (32 x b128 loads)
    bf16x8 w1r[16], w2r[16];
    #pragma unroll
    for (int f = 0; f < 16; ++f) {
        const int mb = f >> 2, kv = f & 3;                 // global mb = wid*4+mb
        w1r[f] = __builtin_bit_cast(bf16x8, wfr[((wid * 4 + mb) * 4 + kv) * 64 + lane]);
        w2r[f] = __builtin_bit_cast(bf16x8, wfr[(32 + (wid * 4 + mb) * 4 + kv) * 64 + lane]);
    }

    // ---- state: this wave's 16 local elems (ch = 64*wid + 16*(e>>2)+4g+(e&3))
    float y[16];
    {
        const f32x4* x4 = (const f32x4*)x;
        #pragma unroll
        for (int cb = 0; cb < 4; ++cb) {
            f32x4 v = x4[(size_t)rowc * 32 + (wid * 4 + cb) * 4 + g];
            y[cb * 4 + 0] = v[0]; y[cb * 4 + 1] = v[1];
            y[cb * 4 + 2] = v[2]; y[cb * 4 + 3] = v[3];
        }
    }
    __syncthreads();

    float U[16], V[16];

    #pragma unroll 1
    for (int st = 0; st < 10; ++st) {
        feval<1>(w1r, w2r, s_bf, argx, hx, lane, g, wid, y, U, V);   // U <- k1
        feval<2>(w1r, w2r, s_bf, argx, hx, lane, g, wid, y, U, V);   // V <- k2
        feval<3>(w1r, w2r, s_bf, argx, hx, lane, g, wid, y, U, V);   // fold k3
        feval<4>(w1r, w2r, s_bf, argx, hx, lane, g, wid, y, U, V);   // y += h/8(U+k4)
    }

    // ---- epilogue: out^T = Wl^T y^T + bl (wave computes out-ch [32*wid,+32))
    argx[2 * wid + 0][lane] = __builtin_bit_cast(uint4, build_frag<1>(y, U, V, 0));
    argx[2 * wid + 1][lane] = __builtin_bit_cast(uint4, build_frag<1>(y, U, V, 1));
    __syncthreads();
    const bf16x8 yf0 = __builtin_bit_cast(bf16x8, argx[0][lane]);
    const bf16x8 yf1 = __builtin_bit_cast(bf16x8, argx[1][lane]);
    const bf16x8 yf2 = __builtin_bit_cast(bf16x8, argx[2][lane]);
    const bf16x8 yf3 = __builtin_bit_cast(bf16x8, argx[3][lane]);

    f32x4 ao[2];
    {
        const f32x4* bl4 = (const f32x4*)bl;
        #pragma unroll
        for (int mb = 0; mb < 2; ++mb) ao[mb] = bl4[(wid * 2 + mb) * 4 + g];
    }
    #pragma unroll
    for (int mb = 0; mb < 2; ++mb) {
        const int fb = 64 + (wid * 2 + mb) * 4;            // Wl frag base
        ao[mb] = MFMA_BF16(__builtin_bit_cast(bf16x8, wfr[(fb + 0) * 64 + lane]), yf0, ao[mb], 0, 0, 0);
        ao[mb] = MFMA_BF16(__builtin_bit_cast(bf16x8, wfr[(fb + 1) * 64 + lane]), yf1, ao[mb], 0, 0, 0);
        ao[mb] = MFMA_BF16(__builtin_bit_cast(bf16x8, wfr[(fb + 2) * 64 + lane]), yf2, ao[mb], 0, 0, 0);
        ao[mb] = MFMA_BF16(__builtin_bit_cast(bf16x8, wfr[(fb + 3) * 64 + lane]), yf3, ao[mb], 0, 0, 0);
    }
    if (row < n) {
        f32x4* out4 = (f32x4*)out;
        #pragma unroll
        for (int mb = 0; mb < 2; ++mb)
            out4[(size_t)row * 16 + (wid * 2 + mb) * 4 + g] = ao[mb];
    }
}

// ---- prep: A-frag-linear bf16 weights into d_ws ----
// A-frag (16x32): lane l, elem j:  row = l&15 (+16*mb),
//                                  k   = 32*kb + 16*(j>>2) + 4*(l>>4) + (j&3)
// wfr[f*64+lane] : f 0..31 = W1 (mb=f>>2,kb=f&3), 32..63 = W2, 64..79 = Wl.
__global__ void prep_kernel(const float* __restrict__ W1, const float* __restrict__ W2,
                            const float* __restrict__ Wl, uint4* __restrict__ wfr)
{
    int t = blockIdx.x * 256 + threadIdx.x;
    if (t >= 80 * 64) return;
    int f = t >> 6, lane = t & 63;
    int gq = lane >> 4, c = lane & 15;
    const float* W; int mb, kv, cols;
    if (f < 32)      { W = W1; mb = f >> 2;        kv = f & 3;        cols = 128; }
    else if (f < 64) { W = W2; mb = (f - 32) >> 2; kv = (f - 32) & 3; cols = 128; }
    else             { W = Wl; mb = (f - 64) >> 2; kv = (f - 64) & 3; cols = 64;  }
    int col = mb * 16 + c;               // output-channel (A row)
    unsigned short v[8];
    #pragma unroll
    for (int j = 0; j < 8; ++j) {
        int k = kv * 32 + (j >> 2) * 16 + gq * 4 + (j & 3);
        v[j] = (unsigned short)__builtin_bit_cast(short, (__bf16)W[k * cols + col]);
    }
    uint4 o;
    o.x = (unsigned)v[0] | ((unsigned)v[1] << 16);
    o.y = (unsigned)v[2] | ((unsigned)v[3] << 16);
    o.z = (unsigned)v[4] | ((unsigned)v[5] << 16);
    o.w = (unsigned)v[6] | ((unsigned)v[7] << 16);
    wfr[t] = o;
}

extern "C" void kernel_launch(void* const* d_in, const int* in_sizes, int n_in,
                              void* d_out, int out_size, void* d_ws, size_t ws_size,
                              hipStream_t stream)
{
    const float* x  = (const float*)d_in[0];
    const float* W1 = (const float*)d_in[1];
    const float* b1 = (const float*)d_in[2];
    const float* W2 = (const float*)d_in[3];
    const float* b2 = (const float*)d_in[4];
    const float* Wl = (const float*)d_in[5];
    const float* bl = (const float*)d_in[6];

    const int n = in_sizes[0] / 128;

    uint4* wfr = (uint4*)d_ws;                       // 80*64*16 = 81920 B

    prep_kernel<<<20, 256, 0, stream>>>(W1, W2, Wl, wfr);

    const int nb = (n + 15) / 16;            // 16 rows per block (2 waves)
    gnode_kernel<<<nb, 128, 0, stream>>>(x, wfr, b1, b2, bl, (float*)d_out, n);
}

// Round 14
// 477.102 us; speedup vs baseline: 8.0409x; 1.0256x over previous
//
#include <hip/hip_runtime.h>
#include <hip/hip_bf16.h>

// GNODE fully fused: y' = relu(y@W1+b1)@W2+b2, RK4(3/8) x10 steps (h=0.1),
// out = y@Wl+bl.  N=200000 rows, 128 ch, 64 out ch.
//
// Round 14 = r13 (split-channel wave pair, weights AGPR-resident, no spill,
// bench 489us, MfmaUtil 40.6 / VALU 47) minus LDS plumbing overhead:
// - exchange reads HALVED: own 2 frags stay in registers; only the other
//   wave's 2 frags are read from LDS (12 -> 4 ds_read_b128 per feval).
//   Weight frags are loaded in wid-RELATIVE kb order [own0,own1,oth0,oth1]
//   so all register indexing stays compile-time (no scratch, rule #20).
// - exchange/bias LDS pointers hoisted once (offsets fold into ds offset:).
// - s_setprio(1) around each 16-MFMA cluster (T5, zero correctness risk).
// Biases stay in LDS: +32 regs would tip per-wave total past 256 and halve
// occupancy (2 waves/SIMD at ~252 total now).
//
// State recurrences (template<MODE>):
//   M1: U<-k1   M2: V<-k2   M3: U<-U+3(V+k3), V<-U-V+k3   M4: y+=h/8(U+k4)
// Layout identity (mfma_f32_16x16x32_bf16, HW-verified m89):
//   D:      ch = 16*mb + 4*(lane>>4) + r,               batch = lane&15
//   B-frag: ch = 32*kb + 16*(j>>2) + 4*(lane>>4)+(j&3),  batch = lane&15
// => frag[kb][j] = state[kb*8+j]; wave wid owns global kb {2wid, 2wid+1}
//    i.e. state elems [16*wid, 16*wid+16) (local e' = e - 16*wid).
// Barrier safety: 2 barriers/feval on alternating buffers (argx, hx) ->
// every buffer rewrite is separated from its previous reads by >=1 barrier.

typedef __attribute__((ext_vector_type(8))) short bf16x8;
typedef __attribute__((ext_vector_type(4))) float f32x4;

constexpr float HS = 0.1f;

__device__ __forceinline__ short bf16s(float f) {
    return __builtin_bit_cast(short, (__bf16)f);      // -> v_cvt_pk_bf16_f32 (paired)
}
__device__ __forceinline__ bf16x8 bc8(uint4 u) { return __builtin_bit_cast(bf16x8, u); }

#define MFMA_BF16 __builtin_amdgcn_mfma_f32_16x16x32_bf16

// B-frag for local kk (0/1) from this wave's 16 local state elems.
template<int M>
__device__ __forceinline__ bf16x8 build_frag(const float (&y)[16], const float (&U)[16],
                                             const float (&V)[16], int kk) {
    bf16x8 f;
    #pragma unroll
    for (int j = 0; j < 8; ++j) {
        const int e = kk * 8 + j;
        float a;
        if (M == 1)      a = y[e];
        else if (M == 2) a = fmaf(HS * (1.f / 3.f), U[e], y[e]);
        else if (M == 3) a = fmaf(-HS * (1.f / 3.f), U[e], fmaf(HS, V[e], y[e]));
        else             a = fmaf(HS, V[e], y[e]);
        f[j] = bf16s(a);
    }
    return f;
}

// One f-eval for this wave's 64-out-ch half.  Weight frags in wid-relative
// kb order: index f = mb*4 + kv_loc, kv_loc 0/1 = own kbs, 2/3 = other's.
template<int M>
__device__ __forceinline__ void feval(const bf16x8 (&w1r)[16], const bf16x8 (&w2r)[16],
                                      const float* __restrict__ sbf1,
                                      const float* __restrict__ sbf2,
                                      uint4* __restrict__ my_arg, const uint4* __restrict__ ot_arg,
                                      uint4* __restrict__ my_h,   const uint4* __restrict__ ot_h,
                                      float (&y)[16], float (&U)[16], float (&V)[16])
{
    // ---- own arg frags (regs) -> LDS; bias init overlaps the barrier
    const bf16x8 a0 = build_frag<M>(y, U, V, 0);
    const bf16x8 a1 = build_frag<M>(y, U, V, 1);
    my_arg[0]  = __builtin_bit_cast(uint4, a0);
    my_arg[64] = __builtin_bit_cast(uint4, a1);
    f32x4 acc[4];
    #pragma unroll
    for (int mb = 0; mb < 4; ++mb) acc[mb] = *(const f32x4*)&sbf1[mb * 16];
    __syncthreads();
    const bf16x8 a2 = bc8(ot_arg[0]);
    const bf16x8 a3 = bc8(ot_arg[64]);

    // ---- matmul1: 16 MFMA (kv_loc 0,1 = a0,a1 from regs; 2,3 = LDS)
    __builtin_amdgcn_s_setprio(1);
    #pragma unroll
    for (int mb = 0; mb < 4; ++mb) acc[mb] = MFMA_BF16(w1r[mb * 4 + 0], a0, acc[mb], 0, 0, 0);
    #pragma unroll
    for (int mb = 0; mb < 4; ++mb) acc[mb] = MFMA_BF16(w1r[mb * 4 + 1], a1, acc[mb], 0, 0, 0);
    #pragma unroll
    for (int mb = 0; mb < 4; ++mb) acc[mb] = MFMA_BF16(w1r[mb * 4 + 2], a2, acc[mb], 0, 0, 0);
    #pragma unroll
    for (int mb = 0; mb < 4; ++mb) acc[mb] = MFMA_BF16(w1r[mb * 4 + 3], a3, acc[mb], 0, 0, 0);
    __builtin_amdgcn_s_setprio(0);

    // ---- relu -> own h frags (adjacent pairs: packable cvt)
    bf16x8 hb0, hb1;
    #pragma unroll
    for (int j = 0; j < 8; ++j) {
        hb0[j] = bf16s(fmaxf(acc[(j >> 2)][j & 3], 0.f));
        hb1[j] = bf16s(fmaxf(acc[2 + (j >> 2)][j & 3], 0.f));
    }
    my_h[0]  = __builtin_bit_cast(uint4, hb0);
    my_h[64] = __builtin_bit_cast(uint4, hb1);
    f32x4 acc2[4];
    #pragma unroll
    for (int mb = 0; mb < 4; ++mb) acc2[mb] = *(const f32x4*)&sbf2[mb * 16];
    __syncthreads();
    const bf16x8 h2 = bc8(ot_h[0]);
    const bf16x8 h3 = bc8(ot_h[64]);

    // ---- matmul2: 16 MFMA
    __builtin_amdgcn_s_setprio(1);
    #pragma unroll
    for (int mb = 0; mb < 4; ++mb) acc2[mb] = MFMA_BF16(w2r[mb * 4 + 0], hb0, acc2[mb], 0, 0, 0);
    #pragma unroll
    for (int mb = 0; mb < 4; ++mb) acc2[mb] = MFMA_BF16(w2r[mb * 4 + 1], hb1, acc2[mb], 0, 0, 0);
    #pragma unroll
    for (int mb = 0; mb < 4; ++mb) acc2[mb] = MFMA_BF16(w2r[mb * 4 + 2], h2, acc2[mb], 0, 0, 0);
    #pragma unroll
    for (int mb = 0; mb < 4; ++mb) acc2[mb] = MFMA_BF16(w2r[mb * 4 + 3], h3, acc2[mb], 0, 0, 0);
    __builtin_amdgcn_s_setprio(0);

    // ---- mode-fused writeback (local e' = 4*mb' + r)
    #pragma unroll
    for (int mb = 0; mb < 4; ++mb)
        #pragma unroll
        for (int r = 0; r < 4; ++r) {
            const int e = mb * 4 + r;
            const float k = acc2[mb][r];
            if (M == 1)      U[e] = k;
            else if (M == 2) V[e] = k;
            else if (M == 3) {
                const float u = U[e], v = V[e];
                U[e] = fmaf(3.f, v + k, u);
                V[e] = u - v + k;
            } else {
                y[e] = fmaf(HS * 0.125f, U[e] + k, y[e]);
            }
        }
}

__global__ __launch_bounds__(128) void gnode_kernel(
    const float* __restrict__ x, const uint4* __restrict__ wfr,
    const float* __restrict__ b1, const float* __restrict__ b2,
    const float* __restrict__ bl, float* __restrict__ out, int n)
{
    __shared__ uint4 argx[4][64];    // 4KB: arg B-frag exchange
    __shared__ uint4 hx[4][64];      // 4KB: hidden B-frag exchange
    __shared__ float s_bf[256];      // 1KB: b1 [0..127], b2 [128..255]

    const int tid  = threadIdx.x;
    const int lane = tid & 63;
    const int wid  = tid >> 6;       // 0/1: which 64-out-ch half this wave owns
    const int g    = lane >> 4;
    const int c16  = lane & 15;
    const int row  = blockIdx.x * 16 + c16;   // this lane's batch row
    const int rowc = row < n ? row : n - 1;

    s_bf[tid]       = b1[tid];       // each wave writes (and later reads) its
    s_bf[128 + tid] = b2[tid];       // own halves -> no cross-wave dependency

    // ---- weights: this wave's halves, wid-RELATIVE kb order [own0,own1,oth0,oth1]
    bf16x8 w1r[16], w2r[16];
    #pragma unroll
    for (int f = 0; f < 16; ++f) {
        const int mb = f >> 2, kv = f & 3;
        const int kg = (kv < 2) ? (2 * wid + kv) : (2 * (1 - wid) + kv - 2);
        w1r[f] = bc8(wfr[((wid * 4 + mb) * 4 + kg) * 64 + lane]);
        w2r[f] = bc8(wfr[(32 + (wid * 4 + mb) * 4 + kg) * 64 + lane]);
    }

    // ---- hoisted LDS pointers
    uint4*       my_arg = &argx[2 * wid][lane];
    const uint4* ot_arg = &argx[2 * (1 - wid)][lane];
    uint4*       my_h   = &hx[2 * wid][lane];
    const uint4* ot_h   = &hx[2 * (1 - wid)][lane];
    const float* sbf1   = &s_bf[wid * 64 + g * 4];
    const float* sbf2   = &s_bf[128 + wid * 64 + g * 4];

    // ---- state: this wave's 16 local elems (ch = 64*wid + 16*(e>>2)+4g+(e&3))
    float y[16];
    {
        const f32x4* x4 = (const f32x4*)x;
        #pragma unroll
        for (int cb = 0; cb < 4; ++cb) {
            f32x4 v = x4[(size_t)rowc * 32 + (wid * 4 + cb) * 4 + g];
            y[cb * 4 + 0] = v[0]; y[cb * 4 + 1] = v[1];
            y[cb * 4 + 2] = v[2]; y[cb * 4 + 3] = v[3];
        }
    }
    __syncthreads();

    float U[16], V[16];

    #pragma unroll 1
    for (int st = 0; st < 10; ++st) {
        feval<1>(w1r, w2r, sbf1, sbf2, my_arg, ot_arg, my_h, ot_h, y, U, V);
        feval<2>(w1r, w2r, sbf1, sbf2, my_arg, ot_arg, my_h, ot_h, y, U, V);
        feval<3>(w1r, w2r, sbf1, sbf2, my_arg, ot_arg, my_h, ot_h, y, U, V);
        feval<4>(w1r, w2r, sbf1, sbf2, my_arg, ot_arg, my_h, ot_h, y, U, V);
    }

    // ---- epilogue: out^T = Wl^T y^T + bl (wave computes out-ch [32*wid,+32))
    const bf16x8 yf0 = build_frag<1>(y, U, V, 0);
    const bf16x8 yf1 = build_frag<1>(y, U, V, 1);
    my_arg[0]  = __builtin_bit_cast(uint4, yf0);
    my_arg[64] = __builtin_bit_cast(uint4, yf1);
    __syncthreads();
    const bf16x8 yf2 = bc8(ot_arg[0]);
    const bf16x8 yf3 = bc8(ot_arg[64]);

    f32x4 ao[2];
    {
        const f32x4* bl4 = (const f32x4*)bl;
        #pragma unroll
        for (int mb = 0; mb < 2; ++mb) ao[mb] = bl4[(wid * 2 + mb) * 4 + g];
    }
    #pragma unroll
    for (int mb = 0; mb < 2; ++mb) {
        const int fb = 64 + (wid * 2 + mb) * 4;            // Wl frag base (global kb order)
        const int k0 = 2 * wid, k1 = 2 * wid + 1;          // own kbs
        const int k2 = 2 * (1 - wid), k3 = k2 + 1;         // other's kbs
        ao[mb] = MFMA_BF16(bc8(wfr[(fb + k0) * 64 + lane]), yf0, ao[mb], 0, 0, 0);
        ao[mb] = MFMA_BF16(bc8(wfr[(fb + k1) * 64 + lane]), yf1, ao[mb], 0, 0, 0);
        ao[mb] = MFMA_BF16(bc8(wfr[(fb + k2) * 64 + lane]), yf2, ao[mb], 0, 0, 0);
        ao[mb] = MFMA_BF16(bc8(wfr[(fb + k3) * 64 + lane]), yf3, ao[mb], 0, 0, 0);
    }
    if (row < n) {
        f32x4* out4 = (f32x4*)out;
        #pragma unroll
        for (int mb = 0; mb < 2; ++mb)
            out4[(size_t)row * 16 + (wid * 2 + mb) * 4 + g] = ao[mb];
    }
}

// ---- prep: A-frag-linear bf16 weights into d_ws ----
// A-frag (16x32): lane l, elem j:  row = l&15 (+16*mb),
//                                  k   = 32*kb + 16*(j>>2) + 4*(l>>4) + (j&3)
// wfr[f*64+lane] : f 0..31 = W1 (mb=f>>2,kb=f&3), 32..63 = W2, 64..79 = Wl.
__global__ void prep_kernel(const float* __restrict__ W1, const float* __restrict__ W2,
                            const float* __restrict__ Wl, uint4* __restrict__ wfr)
{
    int t = blockIdx.x * 256 + threadIdx.x;
    if (t >= 80 * 64) return;
    int f = t >> 6, lane = t & 63;
    int gq = lane >> 4, c = lane & 15;
    const float* W; int mb, kv, cols;
    if (f < 32)      { W = W1; mb = f >> 2;        kv = f & 3;        cols = 128; }
    else if (f < 64) { W = W2; mb = (f - 32) >> 2; kv = (f - 32) & 3; cols = 128; }
    else             { W = Wl; mb = (f - 64) >> 2; kv = (f - 64) & 3; cols = 64;  }
    int col = mb * 16 + c;               // output-channel (A row)
    unsigned short v[8];
    #pragma unroll
    for (int j = 0; j < 8; ++j) {
        int k = kv * 32 + (j >> 2) * 16 + gq * 4 + (j & 3);
        v[j] = (unsigned short)__builtin_bit_cast(short, (__bf16)W[k * cols + col]);
    }
    uint4 o;
    o.x = (unsigned)v[0] | ((unsigned)v[1] << 16);
    o.y = (unsigned)v[2] | ((unsigned)v[3] << 16);
    o.z = (unsigned)v[4] | ((unsigned)v[5] << 16);
    o.w = (unsigned)v[6] | ((unsigned)v[7] << 16);
    wfr[t] = o;
}

extern "C" void kernel_launch(void* const* d_in, const int* in_sizes, int n_in,
                              void* d_out, int out_size, void* d_ws, size_t ws_size,
                              hipStream_t stream)
{
    const float* x  = (const float*)d_in[0];
    const float* W1 = (const float*)d_in[1];
    const float* b1 = (const float*)d_in[2];
    const float* W2 = (const float*)d_in[3];
    const float* b2 = (const float*)d_in[4];
    const float* Wl = (const float*)d_in[5];
    const float* bl = (const float*)d_in[6];

    const int n = in_sizes[0] / 128;

    uint4* wfr = (uint4*)d_ws;                       // 80*64*16 = 81920 B

    prep_kernel<<<20, 256, 0, stream>>>(W1, W2, Wl, wfr);

    const int nb = (n + 15) / 16;            // 16 rows per block (2 waves)
    gnode_kernel<<<nb, 128, 0, stream>>>(x, wfr, b1, b2, bl, (float*)d_out, n);
}